// Round 22
// baseline (142.953 us; speedup 1.0000x reference)
//
#include <hip/hip_runtime.h>
#include <hip/hip_bf16.h>

typedef unsigned short u16;
typedef unsigned int u32;
typedef __attribute__((ext_vector_type(8))) short short8v;   // 8 bf16 = 16B
typedef __attribute__((ext_vector_type(4))) short short4v;   // 4 bf16 = 8B
typedef __attribute__((ext_vector_type(4))) float f32x4;

__device__ inline u16 f2b(float f) {
    __hip_bfloat16 h = __float2bfloat16(f);
    u16 u; __builtin_memcpy(&u, &h, 2); return u;
}
__device__ inline short8v cvt8s(const float* p, float s) {
    const f32x4 a = *(const f32x4*)p;
    const f32x4 b = *(const f32x4*)(p + 4);
    short8v r;
    #pragma unroll
    for (int e = 0; e < 4; ++e) { r[e] = (short)f2b(a[e] * s); r[4 + e] = (short)f2b(b[e] * s); }
    return r;
}

// ---------------------------------------------------------------------------
// Merged converter: x, Wq (x0.125), Wkv, Wo, biases — one launch.
// ---------------------------------------------------------------------------
#define NX8   524288   // 4096*1024/8
#define NWQ8  131072   // 1024*1024/8
#define NWKV8 262144   // 2048*1024/8
#define NWO8  131072   // 1024*1024/8

__global__ __launch_bounds__(256) void conv_all(
    const float* __restrict__ x, const float* __restrict__ Wq,
    const float* __restrict__ Wkv, const float* __restrict__ Wo,
    const float* __restrict__ bq, const float* __restrict__ bkv,
    u16* __restrict__ xb, u16* __restrict__ wqkv, u16* __restrict__ wob,
    float* __restrict__ bqkv)
{
    int i = blockIdx.x * 256 + threadIdx.x;
    if (i < NX8) { *(short8v*)&xb[(size_t)i * 8] = cvt8s(x + (size_t)i * 8, 1.0f); return; }
    i -= NX8;
    if (i < NWQ8) { *(short8v*)&wqkv[(size_t)i * 8] = cvt8s(Wq + (size_t)i * 8, 0.125f); return; }
    i -= NWQ8;
    if (i < NWKV8) {
        *(short8v*)&wqkv[(size_t)(1024 * 1024) + (size_t)i * 8] = cvt8s(Wkv + (size_t)i * 8, 1.0f);
        return;
    }
    i -= NWKV8;
    if (i < NWO8) { *(short8v*)&wob[(size_t)i * 8] = cvt8s(Wo + (size_t)i * 8, 1.0f); return; }
    i -= NWO8;
    if (i < 384) {
        #pragma unroll
        for (int e = 0; e < 8; ++e) {
            const int b = i * 8 + e;
            bqkv[b] = (b < 1024) ? bq[b] * 0.125f : bkv[b - 1024];
        }
    }
}

// ---------------------------------------------------------------------------
// QKV GEMM with fused V-transpose epilogue (round-21 proven).
// ---------------------------------------------------------------------------
__global__ __launch_bounds__(256, 3) void gemm_qkv(
    const u16* __restrict__ Ap, const u16* __restrict__ Bw,
    const float* __restrict__ bias, u16* __restrict__ QKb, u16* __restrict__ VT)
{
    constexpr int K = 1024;
    __shared__ __align__(16) u16 As[128 * 64];
    __shared__ __align__(16) u16 Bs[128 * 64];
    const int tid  = threadIdx.x;
    const int wave = tid >> 6, lane = tid & 63;
    const int l15  = lane & 15, l4 = lane >> 4;
    const int row0 = blockIdx.x * 128, col0 = blockIdx.y * 128;
    const int wm = (wave >> 1) * 64, wn = (wave & 1) * 64;

    f32x4 acc[4][4];
    #pragma unroll
    for (int i = 0; i < 4; ++i)
        #pragma unroll
        for (int j = 0; j < 4; ++j) acc[i][j] = (f32x4)0.f;

    const int lr = lane >> 3;
    const int gch = (lane & 7) ^ lr;

    for (int kt = 0; kt < K; kt += 64) {
        __syncthreads();
        #pragma unroll
        for (int i = 0; i < 4; ++i) {
            const int slab = wave * 32 + i * 8;
            const u16* ga = Ap + (size_t)(row0 + slab + lr) * K + kt + gch * 8;
            const u16* gb = Bw + (size_t)(col0 + slab + lr) * K + kt + gch * 8;
            __builtin_amdgcn_global_load_lds(
                (const __attribute__((address_space(1))) unsigned int*)ga,
                (__attribute__((address_space(3))) unsigned int*)&As[slab * 64], 16, 0, 0);
            __builtin_amdgcn_global_load_lds(
                (const __attribute__((address_space(1))) unsigned int*)gb,
                (__attribute__((address_space(3))) unsigned int*)&Bs[slab * 64], 16, 0, 0);
        }
        __syncthreads();

        #pragma unroll
        for (int kk = 0; kk < 2; ++kk) {
            const int swz = (((kk * 4 + l4) ^ (l15 & 7)) * 8);
            short8v af[4], bf[4];
            #pragma unroll
            for (int i = 0; i < 4; ++i)
                af[i] = *(const short8v*)&As[(wm + i * 16 + l15) * 64 + swz];
            #pragma unroll
            for (int j = 0; j < 4; ++j)
                bf[j] = *(const short8v*)&Bs[(wn + j * 16 + l15) * 64 + swz];
            #pragma unroll
            for (int i = 0; i < 4; ++i)
                #pragma unroll
                for (int j = 0; j < 4; ++j)
                    acc[i][j] = __builtin_amdgcn_mfma_f32_16x16x32_bf16(af[i], bf[j], acc[i][j], 0, 0, 0);
        }
    }

    if (col0 < 2048) {                           // Q/K block -> QKb stride 2048
        #pragma unroll
        for (int i = 0; i < 4; ++i) {
            const int r = row0 + wm + i * 16 + l4 * 4;
            #pragma unroll
            for (int j = 0; j < 4; ++j) {
                const int c = col0 + wn + j * 16 + l15;
                const float bv = bias[c];
                #pragma unroll
                for (int reg = 0; reg < 4; ++reg)
                    QKb[(size_t)(r + reg) * 2048 + c] = f2b(acc[i][j][reg] + bv);
            }
        }
    } else {                                     // V block -> VT[(bi*16+hi)*64+d][n]
        #pragma unroll
        for (int i = 0; i < 4; ++i) {
            const int n0 = row0 + wm + i * 16 + l4 * 4;
            const int bi = n0 >> 11, nl = n0 & 2047;
            #pragma unroll
            for (int j = 0; j < 4; ++j) {
                const int c  = col0 + wn + j * 16 + l15;
                const int hv = c - 2048, hi = hv >> 6, d = hv & 63;
                const float bv = bias[c];
                short4v w;
                #pragma unroll
                for (int reg = 0; reg < 4; ++reg) w[reg] = (short)f2b(acc[i][j][reg] + bv);
                *(short4v*)&VT[((size_t)((bi * 16 + hi) * 64 + d)) * 2048 + nl] = w;
            }
        }
    }
}

// ---------------------------------------------------------------------------
// Out-projection GEMM (round-21 proven), BN=64.
// ---------------------------------------------------------------------------
__global__ __launch_bounds__(256, 3) void gemm_out(
    const u16* __restrict__ Ap, const u16* __restrict__ Bw,
    const float* __restrict__ bias, float* __restrict__ Cp,
    int M, int N, int K)
{
    __shared__ __align__(16) u16 As[128 * 64];
    __shared__ __align__(16) u16 Bs[64 * 64];
    const int tid  = threadIdx.x;
    const int wave = tid >> 6, lane = tid & 63;
    const int l15  = lane & 15, l4 = lane >> 4;
    const int row0 = blockIdx.x * 128, col0 = blockIdx.y * 64;
    const int wm = (wave >> 1) * 64, wn = (wave & 1) * 32;

    f32x4 acc[4][2];
    #pragma unroll
    for (int i = 0; i < 4; ++i)
        #pragma unroll
        for (int j = 0; j < 2; ++j) acc[i][j] = (f32x4)0.f;

    const int lr = lane >> 3;
    const int gch = (lane & 7) ^ lr;

    for (int kt = 0; kt < K; kt += 64) {
        __syncthreads();
        #pragma unroll
        for (int i = 0; i < 4; ++i) {
            const int slab = wave * 32 + i * 8;
            const u16* ga = Ap + (size_t)(row0 + slab + lr) * K + kt + gch * 8;
            __builtin_amdgcn_global_load_lds(
                (const __attribute__((address_space(1))) unsigned int*)ga,
                (__attribute__((address_space(3))) unsigned int*)&As[slab * 64], 16, 0, 0);
        }
        #pragma unroll
        for (int i = 0; i < 2; ++i) {
            const int slab = wave * 16 + i * 8;
            const u16* gb = Bw + (size_t)(col0 + slab + lr) * K + kt + gch * 8;
            __builtin_amdgcn_global_load_lds(
                (const __attribute__((address_space(1))) unsigned int*)gb,
                (__attribute__((address_space(3))) unsigned int*)&Bs[slab * 64], 16, 0, 0);
        }
        __syncthreads();

        #pragma unroll
        for (int kk = 0; kk < 2; ++kk) {
            const int swz = (((kk * 4 + l4) ^ (l15 & 7)) * 8);
            short8v af[4], bf[2];
            #pragma unroll
            for (int i = 0; i < 4; ++i)
                af[i] = *(const short8v*)&As[(wm + i * 16 + l15) * 64 + swz];
            #pragma unroll
            for (int j = 0; j < 2; ++j)
                bf[j] = *(const short8v*)&Bs[(wn + j * 16 + l15) * 64 + swz];
            #pragma unroll
            for (int i = 0; i < 4; ++i)
                #pragma unroll
                for (int j = 0; j < 2; ++j)
                    acc[i][j] = __builtin_amdgcn_mfma_f32_16x16x32_bf16(af[i], bf[j], acc[i][j], 0, 0, 0);
        }
    }

    #pragma unroll
    for (int i = 0; i < 4; ++i) {
        const int r = row0 + wm + i * 16 + l4 * 4;
        #pragma unroll
        for (int j = 0; j < 2; ++j) {
            const int c = col0 + wn + j * 16 + l15;
            const float bv = bias[c];
            #pragma unroll
            for (int reg = 0; reg < 4; ++reg)
                Cp[(size_t)(r + reg) * N + c] = acc[i][j][reg] + bv;
        }
    }
}

// ---------------------------------------------------------------------------
// Flash attention (causal), round-22: UNPAIRED 4-wave blocks, zero idle
// slots (all waves share nt). LPT dispatch: qt = 31 - blockIdx.x so the
// longest blocks launch first; scheduler backfills (1024 blocks, 3/CU).
// Compute body byte-identical to round-19/21 proven swapped-operand form.
// ---------------------------------------------------------------------------
#define ATT_N 2048
#define ATT_D 1024
#define ATT_HD 64
#define QK_LD 2048

__global__ __launch_bounds__(256, 3) void flash_attn_kernel(
    const u16* __restrict__ QK, const u16* __restrict__ VT,
    u16* __restrict__ AO)
{
    const int tid  = threadIdx.x;
    const int wave = tid >> 6, lane = tid & 63;
    const int l15  = lane & 15, l4 = lane >> 4;
    const int qt = 31 - blockIdx.x, hi = blockIdx.y, bi = blockIdx.z;
    const int nt = qt + 1;
    const int qr0 = qt * 64 + wave * 16;

    __shared__ __align__(16) u16 Ks[2][64 * 72];
    __shared__ __align__(16) u16 Vs[2][64 * 72];
    __shared__ __align__(16) u16 Ps[4][16 * 72];   // per-wave Pq[16 q][72]

    const int sr = tid >> 2, sc = tid & 3;          // 64 rows x 4 chunk-pairs
    const int st0 = sr * 72 + sc * 16, st1 = st0 + 8;
    const size_t kv_base = (size_t)bi * ATT_N * QK_LD;
    const size_t vt_base = ((size_t)(bi * 16 + hi)) * 64 * ATT_N;
    const u16* gkb = QK + kv_base + (size_t)sr * QK_LD + 1024 + hi * ATT_HD + sc * 16;
    const u16* gvb = VT + vt_base + (size_t)sr * ATT_N + sc * 16;

    // Q fragments (B-operand)
    const u16* qp = QK + ((size_t)(bi * ATT_N + qr0 + l15)) * QK_LD + hi * ATT_HD;
    const short8v aq0 = *(const short8v*)(qp + l4 * 8);
    const short8v aq1 = *(const short8v*)(qp + 32 + l4 * 8);

    float mrow = -1e30f, lpart = 0.f;          // per-lane: q = l15
    f32x4 oacc[4];
    #pragma unroll
    for (int j = 0; j < 4; ++j) oacc[j] = (f32x4)0.f;

    // prologue: stage tile 0 into buffer 0
    *(short8v*)&Ks[0][st0] = *(const short8v*)gkb;
    *(short8v*)&Ks[0][st1] = *(const short8v*)(gkb + 8);
    *(short8v*)&Vs[0][st0] = *(const short8v*)gvb;
    *(short8v*)&Vs[0][st1] = *(const short8v*)(gvb + 8);

    short8v kr0, kr1, vr0, vr1;
    for (int t = 0; t < nt; ++t) {
        const int cur = t & 1;
        if (t + 1 < nt) {                       // issue next-tile loads (async)
            const u16* nk = gkb + (size_t)(t + 1) * 64 * QK_LD;
            const u16* nv = gvb + (t + 1) * 64;
            kr0 = *(const short8v*)nk; kr1 = *(const short8v*)(nk + 8);
            vr0 = *(const short8v*)nv; vr1 = *(const short8v*)(nv + 8);
        }
        __syncthreads();                        // buf[cur] ready for all waves

        {
            const int kv0 = t * 64;
            const u16* Kc = &Ks[cur][0];
            const u16* Vc = &Vs[cur][0];
            f32x4 s[4];
            #pragma unroll
            for (int tt = 0; tt < 4; ++tt) {
                const int rb = tt * 16 + l15;
                const short8v bk0 = *(const short8v*)&Kc[rb * 72 + l4 * 8];
                const short8v bk1 = *(const short8v*)&Kc[rb * 72 + 32 + l4 * 8];
                s[tt] = __builtin_amdgcn_mfma_f32_16x16x32_bf16(bk0, aq0, (f32x4)0.f, 0, 0, 0);
                s[tt] = __builtin_amdgcn_mfma_f32_16x16x32_bf16(bk1, aq1, s[tt], 0, 0, 0);
            }
            if (t == nt - 1) {                  // diagonal tile: mask (kv > q)
                const int qg = qr0 + l15;
                #pragma unroll
                for (int tt = 0; tt < 4; ++tt)
                    #pragma unroll
                    for (int r = 0; r < 4; ++r) {
                        const int kg = kv0 + tt * 16 + l4 * 4 + r;
                        s[tt][r] = (kg <= qg) ? s[tt][r] : -1e30f;
                    }
            }
            float pm = fmaxf(fmaxf(fmaxf(s[0][0], s[0][1]), fmaxf(s[0][2], s[0][3])),
                             fmaxf(fmaxf(s[1][0], s[1][1]), fmaxf(s[1][2], s[1][3])));
            pm = fmaxf(pm, fmaxf(fmaxf(fmaxf(s[2][0], s[2][1]), fmaxf(s[2][2], s[2][3])),
                                 fmaxf(fmaxf(s[3][0], s[3][1]), fmaxf(s[3][2], s[3][3]))));
            pm = fmaxf(pm, __shfl_xor(pm, 16));
            pm = fmaxf(pm, __shfl_xor(pm, 32));
            const bool need = pm > mrow + 8.f;
            if (__any(need)) {                  // rescale path (rare)
                const float mnew = fmaxf(mrow, pm);
                const float sf = __expf(mrow - mnew);
                mrow = mnew;
                lpart *= sf;
                #pragma unroll
                for (int j = 0; j < 4; ++j) oacc[j] *= sf;
            }
            float sum = 0.f;
            #pragma unroll
            for (int tt = 0; tt < 4; ++tt)
                #pragma unroll
                for (int r = 0; r < 4; ++r) {
                    const float p = __expf(s[tt][r] - mrow);
                    s[tt][r] = p;
                    sum += p;
                }
            lpart += sum;
            // P -> LDS: short4v b64 stores, additive chunk swizzle
            u16* Pw = &Ps[wave][0];
            #pragma unroll
            for (int tt = 0; tt < 4; ++tt) {
                short4v w;
                #pragma unroll
                for (int r = 0; r < 4; ++r) w[r] = (short)f2b(s[tt][r]);
                const int wch = (2 * tt + (l4 >> 1) + l15) & 7;
                *(short4v*)&Pw[l15 * 72 + wch * 8 + (l4 & 1) * 4] = w;
            }
            asm volatile("" ::: "memory");
            const short8v bp0 = *(const short8v*)&Pw[l15 * 72 + ((l4 + l15) & 7) * 8];
            const short8v bp1 = *(const short8v*)&Pw[l15 * 72 + ((4 + l4 + l15) & 7) * 8];
            #pragma unroll
            for (int j = 0; j < 4; ++j) {
                const int rb = j * 16 + l15;
                const short8v bv0 = *(const short8v*)&Vc[rb * 72 + l4 * 8];
                const short8v bv1 = *(const short8v*)&Vc[rb * 72 + 32 + l4 * 8];
                oacc[j] = __builtin_amdgcn_mfma_f32_16x16x32_bf16(bv0, bp0, oacc[j], 0, 0, 0);
                oacc[j] = __builtin_amdgcn_mfma_f32_16x16x32_bf16(bv1, bp1, oacc[j], 0, 0, 0);
            }
        }

        if (t + 1 < nt) {                       // write next tile (vmcnt waits)
            *(short8v*)&Ks[cur ^ 1][st0] = kr0;
            *(short8v*)&Ks[cur ^ 1][st1] = kr1;
            *(short8v*)&Vs[cur ^ 1][st0] = vr0;
            *(short8v*)&Vs[cur ^ 1][st1] = vr1;
        }
    }

    float lrow = lpart;
    lrow += __shfl_xor(lrow, 16);
    lrow += __shfl_xor(lrow, 32);
    const float rinv = 1.f / lrow;

    u16* op = AO + ((size_t)(bi * ATT_N + qr0 + l15)) * ATT_D + hi * ATT_HD;
    #pragma unroll
    for (int j = 0; j < 4; ++j) {
        short4v v;
        #pragma unroll
        for (int reg = 0; reg < 4; ++reg) v[reg] = (short)f2b(oacc[j][reg] * rinv);
        *(short4v*)(op + j * 16 + l4 * 4) = v;
    }
}

// ---------------------------------------------------------------------------
extern "C" void kernel_launch(void* const* d_in, const int* in_sizes, int n_in,
                              void* d_out, int out_size, void* d_ws, size_t ws_size,
                              hipStream_t stream) {
    const float* x   = (const float*)d_in[0];
    const float* Wq  = (const float*)d_in[1];
    const float* bq  = (const float*)d_in[2];
    const float* Wkv = (const float*)d_in[3];
    const float* bkv = (const float*)d_in[4];
    const float* Wo  = (const float*)d_in[5];
    const float* bo  = (const float*)d_in[6];
    float* out = (float*)d_out;

    // ws layout (40.01MB, proven footprint):
    //   xb 8MB @0 | QKb 16MB @8M | VTb 8MB @24M | Wqkvb 6MB @32M |
    //   Wob 2MB @38M | bqkv 12KB @40M.   AOb = xb (dead after gemm_qkv).
    u16* xb    = (u16*)d_ws;
    u16* QKb   = xb  + (size_t)4096 * 1024;
    u16* VTb   = QKb + (size_t)4096 * 2048;
    u16* Wqkvb = VTb + (size_t)4096 * 2048;
    u16* Wob   = Wqkvb + (size_t)3072 * 1024;
    float* bqkv = (float*)(Wob + (size_t)1024 * 1024);
    u16* AOb   = xb;

    dim3 blk(256);
    conv_all<<<dim3(4098), blk, 0, stream>>>(x, Wq, Wkv, Wo, bq, bkv, xb, Wqkvb, Wob, bqkv);
    gemm_qkv<<<dim3(32, 24), blk, 0, stream>>>(xb, Wqkvb, bqkv, QKb, VTb);
    flash_attn_kernel<<<dim3(32, 16, 2), blk, 0, stream>>>(QKb, VTb, AOb);
    gemm_out<<<dim3(32, 16), blk, 0, stream>>>(AOb, Wob, bo, out, 4096, 1024, 1024);
}

// Round 23
// 108.385 us; speedup vs baseline: 1.3189x; 1.3189x over previous
//
#include <hip/hip_runtime.h>
#include <hip/hip_bf16.h>

typedef unsigned short u16;
typedef unsigned int u32;
typedef __attribute__((ext_vector_type(8))) short short8v;   // 8 bf16 = 16B
typedef __attribute__((ext_vector_type(4))) short short4v;   // 4 bf16 = 8B
typedef __attribute__((ext_vector_type(4))) float f32x4;

__device__ inline u16 f2b(float f) {
    __hip_bfloat16 h = __float2bfloat16(f);
    u16 u; __builtin_memcpy(&u, &h, 2); return u;
}
__device__ inline short8v cvt8s(const float* p, float s) {
    const f32x4 a = *(const f32x4*)p;
    const f32x4 b = *(const f32x4*)(p + 4);
    short8v r;
    #pragma unroll
    for (int e = 0; e < 4; ++e) { r[e] = (short)f2b(a[e] * s); r[4 + e] = (short)f2b(b[e] * s); }
    return r;
}

// ---------------------------------------------------------------------------
// Merged converter: x, Wq (x0.125), Wkv, Wo, biases — one launch (r22-proven).
// ---------------------------------------------------------------------------
#define NX8   524288   // 4096*1024/8
#define NWQ8  131072   // 1024*1024/8
#define NWKV8 262144   // 2048*1024/8
#define NWO8  131072   // 1024*1024/8

__global__ __launch_bounds__(256) void conv_all(
    const float* __restrict__ x, const float* __restrict__ Wq,
    const float* __restrict__ Wkv, const float* __restrict__ Wo,
    const float* __restrict__ bq, const float* __restrict__ bkv,
    u16* __restrict__ xb, u16* __restrict__ wqkv, u16* __restrict__ wob,
    float* __restrict__ bqkv)
{
    int i = blockIdx.x * 256 + threadIdx.x;
    if (i < NX8) { *(short8v*)&xb[(size_t)i * 8] = cvt8s(x + (size_t)i * 8, 1.0f); return; }
    i -= NX8;
    if (i < NWQ8) { *(short8v*)&wqkv[(size_t)i * 8] = cvt8s(Wq + (size_t)i * 8, 0.125f); return; }
    i -= NWQ8;
    if (i < NWKV8) {
        *(short8v*)&wqkv[(size_t)(1024 * 1024) + (size_t)i * 8] = cvt8s(Wkv + (size_t)i * 8, 1.0f);
        return;
    }
    i -= NWKV8;
    if (i < NWO8) { *(short8v*)&wob[(size_t)i * 8] = cvt8s(Wo + (size_t)i * 8, 1.0f); return; }
    i -= NWO8;
    if (i < 384) {
        #pragma unroll
        for (int e = 0; e < 8; ++e) {
            const int b = i * 8 + e;
            bqkv[b] = (b < 1024) ? bq[b] * 0.125f : bkv[b - 1024];
        }
    }
}

// ---------------------------------------------------------------------------
// QKV GEMM with fused V-transpose epilogue (round-21 proven).
// ---------------------------------------------------------------------------
__global__ __launch_bounds__(256, 3) void gemm_qkv(
    const u16* __restrict__ Ap, const u16* __restrict__ Bw,
    const float* __restrict__ bias, u16* __restrict__ QKb, u16* __restrict__ VT)
{
    constexpr int K = 1024;
    __shared__ __align__(16) u16 As[128 * 64];
    __shared__ __align__(16) u16 Bs[128 * 64];
    const int tid  = threadIdx.x;
    const int wave = tid >> 6, lane = tid & 63;
    const int l15  = lane & 15, l4 = lane >> 4;
    const int row0 = blockIdx.x * 128, col0 = blockIdx.y * 128;
    const int wm = (wave >> 1) * 64, wn = (wave & 1) * 64;

    f32x4 acc[4][4];
    #pragma unroll
    for (int i = 0; i < 4; ++i)
        #pragma unroll
        for (int j = 0; j < 4; ++j) acc[i][j] = (f32x4)0.f;

    const int lr = lane >> 3;
    const int gch = (lane & 7) ^ lr;

    for (int kt = 0; kt < K; kt += 64) {
        __syncthreads();
        #pragma unroll
        for (int i = 0; i < 4; ++i) {
            const int slab = wave * 32 + i * 8;
            const u16* ga = Ap + (size_t)(row0 + slab + lr) * K + kt + gch * 8;
            const u16* gb = Bw + (size_t)(col0 + slab + lr) * K + kt + gch * 8;
            __builtin_amdgcn_global_load_lds(
                (const __attribute__((address_space(1))) unsigned int*)ga,
                (__attribute__((address_space(3))) unsigned int*)&As[slab * 64], 16, 0, 0);
            __builtin_amdgcn_global_load_lds(
                (const __attribute__((address_space(1))) unsigned int*)gb,
                (__attribute__((address_space(3))) unsigned int*)&Bs[slab * 64], 16, 0, 0);
        }
        __syncthreads();

        #pragma unroll
        for (int kk = 0; kk < 2; ++kk) {
            const int swz = (((kk * 4 + l4) ^ (l15 & 7)) * 8);
            short8v af[4], bf[4];
            #pragma unroll
            for (int i = 0; i < 4; ++i)
                af[i] = *(const short8v*)&As[(wm + i * 16 + l15) * 64 + swz];
            #pragma unroll
            for (int j = 0; j < 4; ++j)
                bf[j] = *(const short8v*)&Bs[(wn + j * 16 + l15) * 64 + swz];
            #pragma unroll
            for (int i = 0; i < 4; ++i)
                #pragma unroll
                for (int j = 0; j < 4; ++j)
                    acc[i][j] = __builtin_amdgcn_mfma_f32_16x16x32_bf16(af[i], bf[j], acc[i][j], 0, 0, 0);
        }
    }

    if (col0 < 2048) {                           // Q/K block -> QKb stride 2048
        #pragma unroll
        for (int i = 0; i < 4; ++i) {
            const int r = row0 + wm + i * 16 + l4 * 4;
            #pragma unroll
            for (int j = 0; j < 4; ++j) {
                const int c = col0 + wn + j * 16 + l15;
                const float bv = bias[c];
                #pragma unroll
                for (int reg = 0; reg < 4; ++reg)
                    QKb[(size_t)(r + reg) * 2048 + c] = f2b(acc[i][j][reg] + bv);
            }
        }
    } else {                                     // V block -> VT[(bi*16+hi)*64+d][n]
        #pragma unroll
        for (int i = 0; i < 4; ++i) {
            const int n0 = row0 + wm + i * 16 + l4 * 4;
            const int bi = n0 >> 11, nl = n0 & 2047;
            #pragma unroll
            for (int j = 0; j < 4; ++j) {
                const int c  = col0 + wn + j * 16 + l15;
                const int hv = c - 2048, hi = hv >> 6, d = hv & 63;
                const float bv = bias[c];
                short4v w;
                #pragma unroll
                for (int reg = 0; reg < 4; ++reg) w[reg] = (short)f2b(acc[i][j][reg] + bv);
                *(short4v*)&VT[((size_t)((bi * 16 + hi) * 64 + d)) * 2048 + nl] = w;
            }
        }
    }
}

// ---------------------------------------------------------------------------
// Out-projection GEMM (round-21 proven), BN=64.
// ---------------------------------------------------------------------------
__global__ __launch_bounds__(256, 3) void gemm_out(
    const u16* __restrict__ Ap, const u16* __restrict__ Bw,
    const float* __restrict__ bias, float* __restrict__ Cp,
    int M, int N, int K)
{
    __shared__ __align__(16) u16 As[128 * 64];
    __shared__ __align__(16) u16 Bs[64 * 64];
    const int tid  = threadIdx.x;
    const int wave = tid >> 6, lane = tid & 63;
    const int l15  = lane & 15, l4 = lane >> 4;
    const int row0 = blockIdx.x * 128, col0 = blockIdx.y * 64;
    const int wm = (wave >> 1) * 64, wn = (wave & 1) * 32;

    f32x4 acc[4][2];
    #pragma unroll
    for (int i = 0; i < 4; ++i)
        #pragma unroll
        for (int j = 0; j < 2; ++j) acc[i][j] = (f32x4)0.f;

    const int lr = lane >> 3;
    const int gch = (lane & 7) ^ lr;

    for (int kt = 0; kt < K; kt += 64) {
        __syncthreads();
        #pragma unroll
        for (int i = 0; i < 4; ++i) {
            const int slab = wave * 32 + i * 8;
            const u16* ga = Ap + (size_t)(row0 + slab + lr) * K + kt + gch * 8;
            __builtin_amdgcn_global_load_lds(
                (const __attribute__((address_space(1))) unsigned int*)ga,
                (__attribute__((address_space(3))) unsigned int*)&As[slab * 64], 16, 0, 0);
        }
        #pragma unroll
        for (int i = 0; i < 2; ++i) {
            const int slab = wave * 16 + i * 8;
            const u16* gb = Bw + (size_t)(col0 + slab + lr) * K + kt + gch * 8;
            __builtin_amdgcn_global_load_lds(
                (const __attribute__((address_space(1))) unsigned int*)gb,
                (__attribute__((address_space(3))) unsigned int*)&Bs[slab * 64], 16, 0, 0);
        }
        __syncthreads();

        #pragma unroll
        for (int kk = 0; kk < 2; ++kk) {
            const int swz = (((kk * 4 + l4) ^ (l15 & 7)) * 8);
            short8v af[4], bf[2];
            #pragma unroll
            for (int i = 0; i < 4; ++i)
                af[i] = *(const short8v*)&As[(wm + i * 16 + l15) * 64 + swz];
            #pragma unroll
            for (int j = 0; j < 2; ++j)
                bf[j] = *(const short8v*)&Bs[(wn + j * 16 + l15) * 64 + swz];
            #pragma unroll
            for (int i = 0; i < 4; ++i)
                #pragma unroll
                for (int j = 0; j < 2; ++j)
                    acc[i][j] = __builtin_amdgcn_mfma_f32_16x16x32_bf16(af[i], bf[j], acc[i][j], 0, 0, 0);
        }
    }

    #pragma unroll
    for (int i = 0; i < 4; ++i) {
        const int r = row0 + wm + i * 16 + l4 * 4;
        #pragma unroll
        for (int j = 0; j < 2; ++j) {
            const int c = col0 + wn + j * 16 + l15;
            const float bv = bias[c];
            #pragma unroll
            for (int reg = 0; reg < 4; ++reg)
                Cp[(size_t)(r + reg) * N + c] = acc[i][j][reg] + bv;
        }
    }
}

// ---------------------------------------------------------------------------
// Flash attention (causal) — ROUND-21 PROVEN kernel (48.7us): 8-wave paired
// blocks (512 thr), dbuf K/V, one barrier/tile; swapped-operand S^T=mfma(K,Q);
// in-reg softmax; additive P swizzle; O^T=mfma(V^T,P^T). QK stride 2048.
// ---------------------------------------------------------------------------
#define ATT_N 2048
#define ATT_D 1024
#define ATT_HD 64
#define QK_LD 2048

__global__ __launch_bounds__(512, 2) void flash_attn_kernel(
    const u16* __restrict__ QK, const u16* __restrict__ VT,
    u16* __restrict__ AO)
{
    const int tid  = threadIdx.x;
    const int wave = tid >> 6, lane = tid & 63;
    const int l15  = lane & 15, l4 = lane >> 4;
    const int pidx = blockIdx.x, hi = blockIdx.y, bi = blockIdx.z;
    const int grp  = wave >> 2, wq = wave & 3;

    const int qt  = grp ? pidx : (31 - pidx);
    const int nt  = qt + 1;
    const int ntmax = 32 - pidx;
    const int qr0 = qt * 64 + wq * 16;

    __shared__ __align__(16) u16 Ks[2][64 * 72];
    __shared__ __align__(16) u16 Vs[2][64 * 72];
    __shared__ __align__(16) u16 Ps[8][16 * 72];   // per-wave Pq[16 q][72]

    const int sr = tid >> 3, sc = tid & 7;
    const int stoff = sr * 72 + sc * 8;
    const size_t kv_base = (size_t)bi * ATT_N * QK_LD;
    const size_t vt_base = ((size_t)(bi * 16 + hi)) * 64 * ATT_N;
    const u16* gkb = QK + kv_base + (size_t)sr * QK_LD + 1024 + hi * ATT_HD + sc * 8;
    const u16* gvb = VT + vt_base + (size_t)sr * ATT_N + sc * 8;

    // Q fragments (B-operand)
    const u16* qp = QK + ((size_t)(bi * ATT_N + qr0 + l15)) * QK_LD + hi * ATT_HD;
    const short8v aq0 = *(const short8v*)(qp + l4 * 8);
    const short8v aq1 = *(const short8v*)(qp + 32 + l4 * 8);

    float mrow = -1e30f, lpart = 0.f;          // per-lane: q = l15
    f32x4 oacc[4];
    #pragma unroll
    for (int j = 0; j < 4; ++j) oacc[j] = (f32x4)0.f;

    // prologue: stage tile 0 into buffer 0
    *(short8v*)&Ks[0][stoff] = *(const short8v*)gkb;
    *(short8v*)&Vs[0][stoff] = *(const short8v*)gvb;

    short8v kreg, vreg;
    for (int t = 0; t < ntmax; ++t) {
        const int cur = t & 1;
        if (t + 1 < ntmax) {
            kreg = *(const short8v*)(gkb + (size_t)(t + 1) * 64 * QK_LD);
            vreg = *(const short8v*)(gvb + (t + 1) * 64);
        }
        __syncthreads();

        if (t < nt) {
            const int kv0 = t * 64;
            const u16* Kc = &Ks[cur][0];
            const u16* Vc = &Vs[cur][0];
            f32x4 s[4];
            #pragma unroll
            for (int tt = 0; tt < 4; ++tt) {
                const int rb = tt * 16 + l15;
                const short8v bk0 = *(const short8v*)&Kc[rb * 72 + l4 * 8];
                const short8v bk1 = *(const short8v*)&Kc[rb * 72 + 32 + l4 * 8];
                s[tt] = __builtin_amdgcn_mfma_f32_16x16x32_bf16(bk0, aq0, (f32x4)0.f, 0, 0, 0);
                s[tt] = __builtin_amdgcn_mfma_f32_16x16x32_bf16(bk1, aq1, s[tt], 0, 0, 0);
            }
            if (t == nt - 1) {                  // diagonal tile: mask (kv > q)
                const int qg = qr0 + l15;
                #pragma unroll
                for (int tt = 0; tt < 4; ++tt)
                    #pragma unroll
                    for (int r = 0; r < 4; ++r) {
                        const int kg = kv0 + tt * 16 + l4 * 4 + r;
                        s[tt][r] = (kg <= qg) ? s[tt][r] : -1e30f;
                    }
            }
            float pm = fmaxf(fmaxf(fmaxf(s[0][0], s[0][1]), fmaxf(s[0][2], s[0][3])),
                             fmaxf(fmaxf(s[1][0], s[1][1]), fmaxf(s[1][2], s[1][3])));
            pm = fmaxf(pm, fmaxf(fmaxf(fmaxf(s[2][0], s[2][1]), fmaxf(s[2][2], s[2][3])),
                                 fmaxf(fmaxf(s[3][0], s[3][1]), fmaxf(s[3][2], s[3][3]))));
            pm = fmaxf(pm, __shfl_xor(pm, 16));
            pm = fmaxf(pm, __shfl_xor(pm, 32));
            const bool need = pm > mrow + 8.f;
            if (__any(need)) {
                const float mnew = fmaxf(mrow, pm);
                const float sf = __expf(mrow - mnew);
                mrow = mnew;
                lpart *= sf;
                #pragma unroll
                for (int j = 0; j < 4; ++j) oacc[j] *= sf;
            }
            float sum = 0.f;
            #pragma unroll
            for (int tt = 0; tt < 4; ++tt)
                #pragma unroll
                for (int r = 0; r < 4; ++r) {
                    const float p = __expf(s[tt][r] - mrow);
                    s[tt][r] = p;
                    sum += p;
                }
            lpart += sum;
            u16* Pw = &Ps[wave][0];
            #pragma unroll
            for (int tt = 0; tt < 4; ++tt) {
                short4v w;
                #pragma unroll
                for (int r = 0; r < 4; ++r) w[r] = (short)f2b(s[tt][r]);
                const int wch = (2 * tt + (l4 >> 1) + l15) & 7;
                *(short4v*)&Pw[l15 * 72 + wch * 8 + (l4 & 1) * 4] = w;
            }
            asm volatile("" ::: "memory");
            const short8v bp0 = *(const short8v*)&Pw[l15 * 72 + ((l4 + l15) & 7) * 8];
            const short8v bp1 = *(const short8v*)&Pw[l15 * 72 + ((4 + l4 + l15) & 7) * 8];
            #pragma unroll
            for (int j = 0; j < 4; ++j) {
                const int rb = j * 16 + l15;
                const short8v bv0 = *(const short8v*)&Vc[rb * 72 + l4 * 8];
                const short8v bv1 = *(const short8v*)&Vc[rb * 72 + 32 + l4 * 8];
                oacc[j] = __builtin_amdgcn_mfma_f32_16x16x32_bf16(bv0, bp0, oacc[j], 0, 0, 0);
                oacc[j] = __builtin_amdgcn_mfma_f32_16x16x32_bf16(bv1, bp1, oacc[j], 0, 0, 0);
            }
        }

        if (t + 1 < ntmax) {
            *(short8v*)&Ks[cur ^ 1][stoff] = kreg;
            *(short8v*)&Vs[cur ^ 1][stoff] = vreg;
        }
    }

    float lrow = lpart;
    lrow += __shfl_xor(lrow, 16);
    lrow += __shfl_xor(lrow, 32);
    const float rinv = 1.f / lrow;

    u16* op = AO + ((size_t)(bi * ATT_N + qr0 + l15)) * ATT_D + hi * ATT_HD;
    #pragma unroll
    for (int j = 0; j < 4; ++j) {
        short4v v;
        #pragma unroll
        for (int reg = 0; reg < 4; ++reg) v[reg] = (short)f2b(oacc[j][reg] * rinv);
        *(short4v*)(op + j * 16 + l4 * 4) = v;
    }
}

// ---------------------------------------------------------------------------
extern "C" void kernel_launch(void* const* d_in, const int* in_sizes, int n_in,
                              void* d_out, int out_size, void* d_ws, size_t ws_size,
                              hipStream_t stream) {
    const float* x   = (const float*)d_in[0];
    const float* Wq  = (const float*)d_in[1];
    const float* bq  = (const float*)d_in[2];
    const float* Wkv = (const float*)d_in[3];
    const float* bkv = (const float*)d_in[4];
    const float* Wo  = (const float*)d_in[5];
    const float* bo  = (const float*)d_in[6];
    float* out = (float*)d_out;

    // ws layout (40.01MB, proven footprint):
    //   xb 8MB @0 | QKb 16MB @8M | VTb 8MB @24M | Wqkvb 6MB @32M |
    //   Wob 2MB @38M | bqkv 12KB @40M.   AOb = xb (dead after gemm_qkv).
    u16* xb    = (u16*)d_ws;
    u16* QKb   = xb  + (size_t)4096 * 1024;
    u16* VTb   = QKb + (size_t)4096 * 2048;
    u16* Wqkvb = VTb + (size_t)4096 * 2048;
    u16* Wob   = Wqkvb + (size_t)3072 * 1024;
    float* bqkv = (float*)(Wob + (size_t)1024 * 1024);
    u16* AOb   = xb;

    dim3 blk(256);
    conv_all<<<dim3(4098), blk, 0, stream>>>(x, Wq, Wkv, Wo, bq, bkv, xb, Wqkvb, Wob, bqkv);
    gemm_qkv<<<dim3(32, 24), blk, 0, stream>>>(xb, Wqkvb, bqkv, QKb, VTb);
    flash_attn_kernel<<<dim3(16, 16, 2), dim3(512), 0, stream>>>(QKb, VTb, AOb);
    gemm_out<<<dim3(32, 16), blk, 0, stream>>>(AOb, Wob, bo, out, 4096, 1024, 1024);
}

// Round 24
// 108.210 us; speedup vs baseline: 1.3211x; 1.0016x over previous
//
#include <hip/hip_runtime.h>
#include <hip/hip_bf16.h>

typedef unsigned short u16;
typedef unsigned int u32;
typedef __attribute__((ext_vector_type(8))) short short8v;   // 8 bf16 = 16B
typedef __attribute__((ext_vector_type(4))) short short4v;   // 4 bf16 = 8B
typedef __attribute__((ext_vector_type(4))) float f32x4;

__device__ inline u16 f2b(float f) {
    __hip_bfloat16 h = __float2bfloat16(f);
    u16 u; __builtin_memcpy(&u, &h, 2); return u;
}
__device__ inline short8v cvt8s(const float* p, float s) {
    const f32x4 a = *(const f32x4*)p;
    const f32x4 b = *(const f32x4*)(p + 4);
    short8v r;
    #pragma unroll
    for (int e = 0; e < 4; ++e) { r[e] = (short)f2b(a[e] * s); r[4 + e] = (short)f2b(b[e] * s); }
    return r;
}

// ---------------------------------------------------------------------------
// Merged converter: x, Wq (x0.125), Wkv, Wo, biases — one launch (proven).
// ---------------------------------------------------------------------------
#define NX8   524288   // 4096*1024/8
#define NWQ8  131072   // 1024*1024/8
#define NWKV8 262144   // 2048*1024/8
#define NWO8  131072   // 1024*1024/8

__global__ __launch_bounds__(256) void conv_all(
    const float* __restrict__ x, const float* __restrict__ Wq,
    const float* __restrict__ Wkv, const float* __restrict__ Wo,
    const float* __restrict__ bq, const float* __restrict__ bkv,
    u16* __restrict__ xb, u16* __restrict__ wqkv, u16* __restrict__ wob,
    float* __restrict__ bqkv)
{
    int i = blockIdx.x * 256 + threadIdx.x;
    if (i < NX8) { *(short8v*)&xb[(size_t)i * 8] = cvt8s(x + (size_t)i * 8, 1.0f); return; }
    i -= NX8;
    if (i < NWQ8) { *(short8v*)&wqkv[(size_t)i * 8] = cvt8s(Wq + (size_t)i * 8, 0.125f); return; }
    i -= NWQ8;
    if (i < NWKV8) {
        *(short8v*)&wqkv[(size_t)(1024 * 1024) + (size_t)i * 8] = cvt8s(Wkv + (size_t)i * 8, 1.0f);
        return;
    }
    i -= NWKV8;
    if (i < NWO8) { *(short8v*)&wob[(size_t)i * 8] = cvt8s(Wo + (size_t)i * 8, 1.0f); return; }
    i -= NWO8;
    if (i < 384) {
        #pragma unroll
        for (int e = 0; e < 8; ++e) {
            const int b = i * 8 + e;
            bqkv[b] = (b < 1024) ? bq[b] * 0.125f : bkv[b - 1024];
        }
    }
}

// ---------------------------------------------------------------------------
// QKV GEMM with fused V-transpose epilogue (round-21 proven).
// ---------------------------------------------------------------------------
__global__ __launch_bounds__(256, 3) void gemm_qkv(
    const u16* __restrict__ Ap, const u16* __restrict__ Bw,
    const float* __restrict__ bias, u16* __restrict__ QKb, u16* __restrict__ VT)
{
    constexpr int K = 1024;
    __shared__ __align__(16) u16 As[128 * 64];
    __shared__ __align__(16) u16 Bs[128 * 64];
    const int tid  = threadIdx.x;
    const int wave = tid >> 6, lane = tid & 63;
    const int l15  = lane & 15, l4 = lane >> 4;
    const int row0 = blockIdx.x * 128, col0 = blockIdx.y * 128;
    const int wm = (wave >> 1) * 64, wn = (wave & 1) * 64;

    f32x4 acc[4][4];
    #pragma unroll
    for (int i = 0; i < 4; ++i)
        #pragma unroll
        for (int j = 0; j < 4; ++j) acc[i][j] = (f32x4)0.f;

    const int lr = lane >> 3;
    const int gch = (lane & 7) ^ lr;

    for (int kt = 0; kt < K; kt += 64) {
        __syncthreads();
        #pragma unroll
        for (int i = 0; i < 4; ++i) {
            const int slab = wave * 32 + i * 8;
            const u16* ga = Ap + (size_t)(row0 + slab + lr) * K + kt + gch * 8;
            const u16* gb = Bw + (size_t)(col0 + slab + lr) * K + kt + gch * 8;
            __builtin_amdgcn_global_load_lds(
                (const __attribute__((address_space(1))) unsigned int*)ga,
                (__attribute__((address_space(3))) unsigned int*)&As[slab * 64], 16, 0, 0);
            __builtin_amdgcn_global_load_lds(
                (const __attribute__((address_space(1))) unsigned int*)gb,
                (__attribute__((address_space(3))) unsigned int*)&Bs[slab * 64], 16, 0, 0);
        }
        __syncthreads();

        #pragma unroll
        for (int kk = 0; kk < 2; ++kk) {
            const int swz = (((kk * 4 + l4) ^ (l15 & 7)) * 8);
            short8v af[4], bf[4];
            #pragma unroll
            for (int i = 0; i < 4; ++i)
                af[i] = *(const short8v*)&As[(wm + i * 16 + l15) * 64 + swz];
            #pragma unroll
            for (int j = 0; j < 4; ++j)
                bf[j] = *(const short8v*)&Bs[(wn + j * 16 + l15) * 64 + swz];
            #pragma unroll
            for (int i = 0; i < 4; ++i)
                #pragma unroll
                for (int j = 0; j < 4; ++j)
                    acc[i][j] = __builtin_amdgcn_mfma_f32_16x16x32_bf16(af[i], bf[j], acc[i][j], 0, 0, 0);
        }
    }

    if (col0 < 2048) {                           // Q/K block -> QKb stride 2048
        #pragma unroll
        for (int i = 0; i < 4; ++i) {
            const int r = row0 + wm + i * 16 + l4 * 4;
            #pragma unroll
            for (int j = 0; j < 4; ++j) {
                const int c = col0 + wn + j * 16 + l15;
                const float bv = bias[c];
                #pragma unroll
                for (int reg = 0; reg < 4; ++reg)
                    QKb[(size_t)(r + reg) * 2048 + c] = f2b(acc[i][j][reg] + bv);
            }
        }
    } else {                                     // V block -> VT[(bi*16+hi)*64+d][n]
        #pragma unroll
        for (int i = 0; i < 4; ++i) {
            const int n0 = row0 + wm + i * 16 + l4 * 4;
            const int bi = n0 >> 11, nl = n0 & 2047;
            #pragma unroll
            for (int j = 0; j < 4; ++j) {
                const int c  = col0 + wn + j * 16 + l15;
                const int hv = c - 2048, hi = hv >> 6, d = hv & 63;
                const float bv = bias[c];
                short4v w;
                #pragma unroll
                for (int reg = 0; reg < 4; ++reg) w[reg] = (short)f2b(acc[i][j][reg] + bv);
                *(short4v*)&VT[((size_t)((bi * 16 + hi) * 64 + d)) * 2048 + nl] = w;
            }
        }
    }
}

// ---------------------------------------------------------------------------
// Out-projection GEMM (round-21 proven), BN=64.
// ---------------------------------------------------------------------------
__global__ __launch_bounds__(256, 3) void gemm_out(
    const u16* __restrict__ Ap, const u16* __restrict__ Bw,
    const float* __restrict__ bias, float* __restrict__ Cp,
    int M, int N, int K)
{
    __shared__ __align__(16) u16 As[128 * 64];
    __shared__ __align__(16) u16 Bs[64 * 64];
    const int tid  = threadIdx.x;
    const int wave = tid >> 6, lane = tid & 63;
    const int l15  = lane & 15, l4 = lane >> 4;
    const int row0 = blockIdx.x * 128, col0 = blockIdx.y * 64;
    const int wm = (wave >> 1) * 64, wn = (wave & 1) * 32;

    f32x4 acc[4][2];
    #pragma unroll
    for (int i = 0; i < 4; ++i)
        #pragma unroll
        for (int j = 0; j < 2; ++j) acc[i][j] = (f32x4)0.f;

    const int lr = lane >> 3;
    const int gch = (lane & 7) ^ lr;

    for (int kt = 0; kt < K; kt += 64) {
        __syncthreads();
        #pragma unroll
        for (int i = 0; i < 4; ++i) {
            const int slab = wave * 32 + i * 8;
            const u16* ga = Ap + (size_t)(row0 + slab + lr) * K + kt + gch * 8;
            __builtin_amdgcn_global_load_lds(
                (const __attribute__((address_space(1))) unsigned int*)ga,
                (__attribute__((address_space(3))) unsigned int*)&As[slab * 64], 16, 0, 0);
        }
        #pragma unroll
        for (int i = 0; i < 2; ++i) {
            const int slab = wave * 16 + i * 8;
            const u16* gb = Bw + (size_t)(col0 + slab + lr) * K + kt + gch * 8;
            __builtin_amdgcn_global_load_lds(
                (const __attribute__((address_space(1))) unsigned int*)gb,
                (__attribute__((address_space(3))) unsigned int*)&Bs[slab * 64], 16, 0, 0);
        }
        __syncthreads();

        #pragma unroll
        for (int kk = 0; kk < 2; ++kk) {
            const int swz = (((kk * 4 + l4) ^ (l15 & 7)) * 8);
            short8v af[4], bf[2];
            #pragma unroll
            for (int i = 0; i < 4; ++i)
                af[i] = *(const short8v*)&As[(wm + i * 16 + l15) * 64 + swz];
            #pragma unroll
            for (int j = 0; j < 2; ++j)
                bf[j] = *(const short8v*)&Bs[(wn + j * 16 + l15) * 64 + swz];
            #pragma unroll
            for (int i = 0; i < 4; ++i)
                #pragma unroll
                for (int j = 0; j < 2; ++j)
                    acc[i][j] = __builtin_amdgcn_mfma_f32_16x16x32_bf16(af[i], bf[j], acc[i][j], 0, 0, 0);
        }
    }

    #pragma unroll
    for (int i = 0; i < 4; ++i) {
        const int r = row0 + wm + i * 16 + l4 * 4;
        #pragma unroll
        for (int j = 0; j < 2; ++j) {
            const int c = col0 + wn + j * 16 + l15;
            const float bv = bias[c];
            #pragma unroll
            for (int reg = 0; reg < 4; ++reg)
                Cp[(size_t)(r + reg) * N + c] = acc[i][j][reg] + bv;
        }
    }
}

// ---------------------------------------------------------------------------
// Flash attention (causal) — r21 proven structure + r24 scheduling pack:
// (a) V-fragment loads hoisted BEFORE softmax (frees them from the P-store
//     memory clobber; LDS latency overlaps the exp/max VALU chain),
// (b) s_setprio(1) around both MFMA clusters (T5; 2 independent blocks/CU
//     at different phases = m191's positive regime).
// ---------------------------------------------------------------------------
#define ATT_N 2048
#define ATT_D 1024
#define ATT_HD 64
#define QK_LD 2048

__global__ __launch_bounds__(512, 2) void flash_attn_kernel(
    const u16* __restrict__ QK, const u16* __restrict__ VT,
    u16* __restrict__ AO)
{
    const int tid  = threadIdx.x;
    const int wave = tid >> 6, lane = tid & 63;
    const int l15  = lane & 15, l4 = lane >> 4;
    const int pidx = blockIdx.x, hi = blockIdx.y, bi = blockIdx.z;
    const int grp  = wave >> 2, wq = wave & 3;

    const int qt  = grp ? pidx : (31 - pidx);
    const int nt  = qt + 1;
    const int ntmax = 32 - pidx;
    const int qr0 = qt * 64 + wq * 16;

    __shared__ __align__(16) u16 Ks[2][64 * 72];
    __shared__ __align__(16) u16 Vs[2][64 * 72];
    __shared__ __align__(16) u16 Ps[8][16 * 72];   // per-wave Pq[16 q][72]

    const int sr = tid >> 3, sc = tid & 7;
    const int stoff = sr * 72 + sc * 8;
    const size_t kv_base = (size_t)bi * ATT_N * QK_LD;
    const size_t vt_base = ((size_t)(bi * 16 + hi)) * 64 * ATT_N;
    const u16* gkb = QK + kv_base + (size_t)sr * QK_LD + 1024 + hi * ATT_HD + sc * 8;
    const u16* gvb = VT + vt_base + (size_t)sr * ATT_N + sc * 8;

    // Q fragments (B-operand)
    const u16* qp = QK + ((size_t)(bi * ATT_N + qr0 + l15)) * QK_LD + hi * ATT_HD;
    const short8v aq0 = *(const short8v*)(qp + l4 * 8);
    const short8v aq1 = *(const short8v*)(qp + 32 + l4 * 8);

    float mrow = -1e30f, lpart = 0.f;          // per-lane: q = l15
    f32x4 oacc[4];
    #pragma unroll
    for (int j = 0; j < 4; ++j) oacc[j] = (f32x4)0.f;

    // prologue: stage tile 0 into buffer 0
    *(short8v*)&Ks[0][stoff] = *(const short8v*)gkb;
    *(short8v*)&Vs[0][stoff] = *(const short8v*)gvb;

    short8v kreg, vreg;
    for (int t = 0; t < ntmax; ++t) {
        const int cur = t & 1;
        if (t + 1 < ntmax) {
            kreg = *(const short8v*)(gkb + (size_t)(t + 1) * 64 * QK_LD);
            vreg = *(const short8v*)(gvb + (t + 1) * 64);
        }
        __syncthreads();

        if (t < nt) {
            const int kv0 = t * 64;
            const u16* Kc = &Ks[cur][0];
            const u16* Vc = &Vs[cur][0];
            // S^T = K · Q^T
            f32x4 s[4];
            __builtin_amdgcn_s_setprio(1);
            #pragma unroll
            for (int tt = 0; tt < 4; ++tt) {
                const int rb = tt * 16 + l15;
                const short8v bk0 = *(const short8v*)&Kc[rb * 72 + l4 * 8];
                const short8v bk1 = *(const short8v*)&Kc[rb * 72 + 32 + l4 * 8];
                s[tt] = __builtin_amdgcn_mfma_f32_16x16x32_bf16(bk0, aq0, (f32x4)0.f, 0, 0, 0);
                s[tt] = __builtin_amdgcn_mfma_f32_16x16x32_bf16(bk1, aq1, s[tt], 0, 0, 0);
            }
            __builtin_amdgcn_s_setprio(0);
            // V fragments now (independent of P; overlap softmax VALU below)
            short8v bv0[4], bv1[4];
            #pragma unroll
            for (int j = 0; j < 4; ++j) {
                const int rb = j * 16 + l15;
                bv0[j] = *(const short8v*)&Vc[rb * 72 + l4 * 8];
                bv1[j] = *(const short8v*)&Vc[rb * 72 + 32 + l4 * 8];
            }
            if (t == nt - 1) {                  // diagonal tile: mask (kv > q)
                const int qg = qr0 + l15;
                #pragma unroll
                for (int tt = 0; tt < 4; ++tt)
                    #pragma unroll
                    for (int r = 0; r < 4; ++r) {
                        const int kg = kv0 + tt * 16 + l4 * 4 + r;
                        s[tt][r] = (kg <= qg) ? s[tt][r] : -1e30f;
                    }
            }
            float pm = fmaxf(fmaxf(fmaxf(s[0][0], s[0][1]), fmaxf(s[0][2], s[0][3])),
                             fmaxf(fmaxf(s[1][0], s[1][1]), fmaxf(s[1][2], s[1][3])));
            pm = fmaxf(pm, fmaxf(fmaxf(fmaxf(s[2][0], s[2][1]), fmaxf(s[2][2], s[2][3])),
                                 fmaxf(fmaxf(s[3][0], s[3][1]), fmaxf(s[3][2], s[3][3]))));
            pm = fmaxf(pm, __shfl_xor(pm, 16));
            pm = fmaxf(pm, __shfl_xor(pm, 32));
            const bool need = pm > mrow + 8.f;
            if (__any(need)) {                  // rescale path (rare)
                const float mnew = fmaxf(mrow, pm);
                const float sf = __expf(mrow - mnew);
                mrow = mnew;
                lpart *= sf;
                #pragma unroll
                for (int j = 0; j < 4; ++j) oacc[j] *= sf;
            }
            float sum = 0.f;
            #pragma unroll
            for (int tt = 0; tt < 4; ++tt)
                #pragma unroll
                for (int r = 0; r < 4; ++r) {
                    const float p = __expf(s[tt][r] - mrow);
                    s[tt][r] = p;
                    sum += p;
                }
            lpart += sum;
            // P -> LDS: short4v b64 stores, additive chunk swizzle
            u16* Pw = &Ps[wave][0];
            #pragma unroll
            for (int tt = 0; tt < 4; ++tt) {
                short4v w;
                #pragma unroll
                for (int r = 0; r < 4; ++r) w[r] = (short)f2b(s[tt][r]);
                const int wch = (2 * tt + (l4 >> 1) + l15) & 7;
                *(short4v*)&Pw[l15 * 72 + wch * 8 + (l4 & 1) * 4] = w;
            }
            asm volatile("" ::: "memory");      // order P writes before P reads
            const short8v bp0 = *(const short8v*)&Pw[l15 * 72 + ((l4 + l15) & 7) * 8];
            const short8v bp1 = *(const short8v*)&Pw[l15 * 72 + ((4 + l4 + l15) & 7) * 8];
            // O^T += V^T · P^T (V already in registers)
            __builtin_amdgcn_s_setprio(1);
            #pragma unroll
            for (int j = 0; j < 4; ++j) {
                oacc[j] = __builtin_amdgcn_mfma_f32_16x16x32_bf16(bv0[j], bp0, oacc[j], 0, 0, 0);
                oacc[j] = __builtin_amdgcn_mfma_f32_16x16x32_bf16(bv1[j], bp1, oacc[j], 0, 0, 0);
            }
            __builtin_amdgcn_s_setprio(0);
        }

        if (t + 1 < ntmax) {
            *(short8v*)&Ks[cur ^ 1][stoff] = kreg;
            *(short8v*)&Vs[cur ^ 1][stoff] = vreg;
        }
    }

    float lrow = lpart;
    lrow += __shfl_xor(lrow, 16);
    lrow += __shfl_xor(lrow, 32);
    const float rinv = 1.f / lrow;

    u16* op = AO + ((size_t)(bi * ATT_N + qr0 + l15)) * ATT_D + hi * ATT_HD;
    #pragma unroll
    for (int j = 0; j < 4; ++j) {
        short4v v;
        #pragma unroll
        for (int reg = 0; reg < 4; ++reg) v[reg] = (short)f2b(oacc[j][reg] * rinv);
        *(short4v*)(op + j * 16 + l4 * 4) = v;
    }
}

// ---------------------------------------------------------------------------
extern "C" void kernel_launch(void* const* d_in, const int* in_sizes, int n_in,
                              void* d_out, int out_size, void* d_ws, size_t ws_size,
                              hipStream_t stream) {
    const float* x   = (const float*)d_in[0];
    const float* Wq  = (const float*)d_in[1];
    const float* bq  = (const float*)d_in[2];
    const float* Wkv = (const float*)d_in[3];
    const float* bkv = (const float*)d_in[4];
    const float* Wo  = (const float*)d_in[5];
    const float* bo  = (const float*)d_in[6];
    float* out = (float*)d_out;

    // ws layout (40.01MB, proven footprint):
    //   xb 8MB @0 | QKb 16MB @8M | VTb 8MB @24M | Wqkvb 6MB @32M |
    //   Wob 2MB @38M | bqkv 12KB @40M.   AOb = xb (dead after gemm_qkv).
    u16* xb    = (u16*)d_ws;
    u16* QKb   = xb  + (size_t)4096 * 1024;
    u16* VTb   = QKb + (size_t)4096 * 2048;
    u16* Wqkvb = VTb + (size_t)4096 * 2048;
    u16* Wob   = Wqkvb + (size_t)3072 * 1024;
    float* bqkv = (float*)(Wob + (size_t)1024 * 1024);
    u16* AOb   = xb;

    dim3 blk(256);
    conv_all<<<dim3(4098), blk, 0, stream>>>(x, Wq, Wkv, Wo, bq, bkv, xb, Wqkvb, Wob, bqkv);
    gemm_qkv<<<dim3(32, 24), blk, 0, stream>>>(xb, Wqkvb, bqkv, QKb, VTb);
    flash_attn_kernel<<<dim3(16, 16, 2), dim3(512), 0, stream>>>(QKb, VTb, AOb);
    gemm_out<<<dim3(32, 16), blk, 0, stream>>>(AOb, Wob, bo, out, 4096, 1024, 1024);
}